// Round 1
// baseline (180.853 us; speedup 1.0000x reference)
//
#include <hip/hip_runtime.h>

#define NBATCH 128
#define NANCH  8732
#define NCLS   21

#define K1_THREADS 256
#define APT 4                       // anchors per thread in kernel 1
#define APB (K1_THREADS * APT)      // 1024 anchors per block
#define BPB ((NANCH + APB - 1) / APB)  // 9 blocks per batch

struct BatchAcc {
    float loc;       // masked smooth-L1 sum
    float sum_all;   // sum of CE over all anchors
    float sum_pos;   // sum of CE over positive anchors
    unsigned cnt;    // positive anchor count
};

// ---------------------------------------------------------------- helpers
__device__ __forceinline__ float waveReduceF(float v) {
    #pragma unroll
    for (int o = 32; o > 0; o >>= 1) v += __shfl_down(v, o, 64);
    return v;
}
__device__ __forceinline__ unsigned waveReduceU(unsigned v) {
    #pragma unroll
    for (int o = 32; o > 0; o >>= 1) v += __shfl_down(v, o, 64);
    return v;
}

// per-anchor cross entropy: logsumexp(row) - row[lbl]
__device__ __forceinline__ float compute_con(const float* __restrict__ row, int lbl) {
    float m = row[0];
    #pragma unroll
    for (int c = 1; c < NCLS; ++c) m = fmaxf(m, row[c]);
    float s = 0.f;
    #pragma unroll
    for (int c = 0; c < NCLS; ++c) s += __expf(row[c] - m);
    return m + __logf(s) - row[lbl];
}

// ---------------------------------------------------------------- kernel 0
__global__ void init_kernel(BatchAcc* __restrict__ acc, float* __restrict__ out) {
    int i = threadIdx.x;
    if (i < NBATCH) acc[i] = BatchAcc{0.f, 0.f, 0.f, 0u};
    if (i == 0) out[0] = 0.f;
}

// ---------------------------------------------------------------- kernel 1
__global__ __launch_bounds__(K1_THREADS) void anchor_kernel(
    const float* __restrict__ loc_out,   // [B,A,4]
    const float* __restrict__ cls_out,   // [B,A,C]
    const float* __restrict__ loc_lab,   // [B,A,4]
    const int*   __restrict__ labels,    // [B,A]
    BatchAcc* __restrict__ acc)
{
    const int b     = blockIdx.x / BPB;
    const int chunk = blockIdx.x % BPB;
    const int tid   = threadIdx.x;

    float loc_s = 0.f, all_s = 0.f, pos_s = 0.f;
    unsigned cnt = 0;

    #pragma unroll
    for (int i = 0; i < APT; ++i) {
        int a = chunk * APB + i * K1_THREADS + tid;
        if (a < NANCH) {
            size_t ba = (size_t)b * NANCH + a;
            int lbl = labels[ba];
            const float* row = cls_out + ba * NCLS;
            float con = compute_con(row, lbl);
            all_s += con;
            if (lbl > 0) {
                pos_s += con;
                cnt++;
                const float* lo = loc_out + ba * 4;
                const float* ll = loc_lab + ba * 4;
                float sl = 0.f;
                #pragma unroll
                for (int j = 0; j < 4; ++j) {
                    float d  = lo[j] - ll[j];
                    float ad = fabsf(d);
                    sl += (ad < 1.f) ? 0.5f * d * d : (ad - 0.5f);
                }
                loc_s += sl;
            }
        }
    }

    // block reduction: wave shuffle then LDS
    loc_s = waveReduceF(loc_s);
    all_s = waveReduceF(all_s);
    pos_s = waveReduceF(pos_s);
    cnt   = waveReduceU(cnt);

    __shared__ float sLoc[4], sAll[4], sPos[4];
    __shared__ unsigned sCnt[4];
    int w = tid >> 6, lane = tid & 63;
    if (lane == 0) { sLoc[w] = loc_s; sAll[w] = all_s; sPos[w] = pos_s; sCnt[w] = cnt; }
    __syncthreads();
    if (tid == 0) {
        float L = 0.f, S = 0.f, P = 0.f; unsigned Cc = 0;
        #pragma unroll
        for (int i = 0; i < 4; ++i) { L += sLoc[i]; S += sAll[i]; P += sPos[i]; Cc += sCnt[i]; }
        atomicAdd(&acc[b].loc, L);
        atomicAdd(&acc[b].sum_all, S);
        atomicAdd(&acc[b].sum_pos, P);
        atomicAdd(&acc[b].cnt, Cc);
    }
}

// ---------------------------------------------------------------- kernel 2
__global__ __launch_bounds__(256) void finalize_kernel(
    const float* __restrict__ cls_out,
    const int*   __restrict__ labels,
    const BatchAcc* __restrict__ acc,
    float* __restrict__ out)
{
    const int b   = blockIdx.x;
    const int tid = threadIdx.x;
    BatchAcc a = acc[b];

    long long k = (long long)3 * (long long)a.cnt;
    if (k > NANCH) k = NANCH;
    if (k == 0) k = 3;

    float con_loss;

    if (k >= NANCH) {
        // neg_mask is all-ones: con_loss = sum(con*(mask+1))
        con_loss = a.sum_all + a.sum_pos;
        if (tid == 0) {
            float denom = (a.cnt != 0u) ? (float)a.cnt : 1.f;
            atomicAdd(out, (a.loc + con_loss) / denom * (1.f / NBATCH));
        }
        return;
    }

    // ---------------- cold general path: exact top-k of con_neg ----------------
    __shared__ float    sF[256];
    __shared__ unsigned sU[256];
    __shared__ float    bcastF;
    __shared__ unsigned bcastU;

    // count of con_neg > t (con_neg = 0 for positives, so only negatives counted for t >= 0)
    auto count_gt = [&](float t) -> unsigned {
        unsigned c = 0;
        for (int an = tid; an < NANCH; an += 256) {
            size_t ba = (size_t)b * NANCH + an;
            int lbl = labels[ba];
            if (lbl > 0) continue;
            float con = compute_con(cls_out + ba * NCLS, lbl);
            if (con > t) c++;
        }
        sU[tid] = c; __syncthreads();
        for (int o = 128; o > 0; o >>= 1) {
            if (tid < o) sU[tid] += sU[tid + o];
            __syncthreads();
        }
        unsigned r = sU[0]; __syncthreads();
        return r;
    };

    unsigned cpos = count_gt(0.0f);  // negatives with strictly positive CE
    float negpart = 0.f;

    if ((unsigned long long)k <= (unsigned long long)cpos) {
        // k-th largest value is > 0; binary search on float bit pattern
        unsigned lo = 0u, hi = 0x7F800000u;  // count(>lo) >= k, count(>hi) < k
        while (hi - lo > 1u) {
            unsigned mid = lo + (hi - lo) / 2u;
            unsigned c = count_gt(__uint_as_float(mid));
            if (c >= (unsigned)k) lo = mid; else hi = mid;
        }
        float v = __uint_as_float(hi);  // the k-th largest value
        // sum of values strictly above v, plus ties at v (all negatives, value-exact)
        float ss = 0.f; unsigned c1 = 0;
        for (int an = tid; an < NANCH; an += 256) {
            size_t ba = (size_t)b * NANCH + an;
            int lbl = labels[ba];
            if (lbl > 0) continue;
            float con = compute_con(cls_out + ba * NCLS, lbl);
            if (con > v) { ss += con; c1++; }
        }
        sF[tid] = ss; sU[tid] = c1; __syncthreads();
        for (int o = 128; o > 0; o >>= 1) {
            if (tid < o) { sF[tid] += sF[tid + o]; sU[tid] += sU[tid + o]; }
            __syncthreads();
        }
        if (tid == 0) { bcastF = sF[0] + (float)((unsigned)k - sU[0]) * v; }
        __syncthreads();
        negpart = bcastF;
    } else {
        // k exceeds the strictly-positive negatives: all of them selected, plus the
        // first (k - cpos) zero-valued entries in index order (stable argsort tie rule).
        if (tid == 0) {
            float np = 0.f;
            unsigned m = (unsigned)k - cpos;
            for (int an = 0; an < NANCH; ++an) {
                size_t ba = (size_t)b * NANCH + an;
                int lbl = labels[ba];
                float con = compute_con(cls_out + ba * NCLS, lbl);
                float cneg = (lbl > 0) ? 0.f : con;
                if (cneg > 0.f) np += con;
                else if (m > 0u) { np += con; m--; }
            }
            bcastF = np;
        }
        __syncthreads();
        negpart = bcastF;
    }

    con_loss = a.sum_pos + negpart;
    if (tid == 0) {
        float denom = (a.cnt != 0u) ? (float)a.cnt : 1.f;
        atomicAdd(out, (a.loc + con_loss) / denom * (1.f / NBATCH));
    }
}

// ---------------------------------------------------------------- launch
extern "C" void kernel_launch(void* const* d_in, const int* in_sizes, int n_in,
                              void* d_out, int out_size, void* d_ws, size_t ws_size,
                              hipStream_t stream) {
    const float* loc_out = (const float*)d_in[0];
    const float* cls_out = (const float*)d_in[1];
    const float* loc_lab = (const float*)d_in[2];
    const int*   labels  = (const int*)d_in[3];
    float* out = (float*)d_out;
    BatchAcc* acc = (BatchAcc*)d_ws;   // needs 128*16 = 2 KB of ws

    init_kernel<<<1, 256, 0, stream>>>(acc, out);
    anchor_kernel<<<NBATCH * BPB, K1_THREADS, 0, stream>>>(loc_out, cls_out, loc_lab, labels, acc);
    finalize_kernel<<<NBATCH, 256, 0, stream>>>(cls_out, labels, acc, out);
}